// Round 1
// baseline (19920.946 us; speedup 1.0000x reference)
//
#include <hip/hip_runtime.h>
#include <hip/hip_bf16.h>
#include <math.h>

#define B_ 16
#define L_ 100
#define D_ 512
#define HW_ 16384
#define H_ 8

// ---------------------------------------------------------------------------
// Generic tiled GEMM:  C = alpha*(A @ B^T) [+ bias] [+ residual] [relu]
// A: MxK (lda), B: NxK (ldb), C/Cres: MxN (ldc). Batched via blockIdx.z:
//   aOff = z*sA; bOff = (z%zmod)*sB; cOff = (z/zmod)*sC1 + (z%zmod)*sC2
// 64x64 tile, BK=16, 4x4 per thread (strided by 16 for bank-friendliness).
// ---------------------------------------------------------------------------
__global__ __launch_bounds__(256) void gemm_bt(
    const float* __restrict__ A, const float* __restrict__ Bm,
    const float* __restrict__ Cres, const float* __restrict__ bias,
    float* __restrict__ C,
    int M, int N, int K, int lda, int ldb, int ldc,
    int zmod, long sA, long sB, long sC1, long sC2,
    float alpha, int relu)
{
    const int z = blockIdx.z;
    const long aOff = (long)z * sA;
    const long bOff = (long)(z % zmod) * sB;
    const long cOff = (long)(z / zmod) * sC1 + (long)(z % zmod) * sC2;

    __shared__ float As[16][65];
    __shared__ float Bs[16][65];

    const int tid = threadIdx.x;
    const int tx = tid & 15, ty = tid >> 4;
    const int m0 = blockIdx.y * 64, n0 = blockIdx.x * 64;
    const int lr = tid & 63;          // staging row within tile
    const int lk = (tid >> 6) * 4;    // staging k quad

    float acc[4][4];
#pragma unroll
    for (int i = 0; i < 4; ++i)
#pragma unroll
        for (int j = 0; j < 4; ++j) acc[i][j] = 0.f;

    for (int k0 = 0; k0 < K; k0 += 16) {
        __syncthreads();
        {
            float4 v = make_float4(0.f, 0.f, 0.f, 0.f);
            const int gr = m0 + lr;
            if (gr < M) v = *(const float4*)&A[aOff + (long)gr * lda + k0 + lk];
            As[lk + 0][lr] = v.x; As[lk + 1][lr] = v.y;
            As[lk + 2][lr] = v.z; As[lk + 3][lr] = v.w;
            const float4 w = *(const float4*)&Bm[bOff + (long)(n0 + lr) * ldb + k0 + lk];
            Bs[lk + 0][lr] = w.x; Bs[lk + 1][lr] = w.y;
            Bs[lk + 2][lr] = w.z; Bs[lk + 3][lr] = w.w;
        }
        __syncthreads();
#pragma unroll
        for (int k = 0; k < 16; ++k) {
            float a[4], bb[4];
#pragma unroll
            for (int i = 0; i < 4; ++i) a[i] = As[k][ty + 16 * i];
#pragma unroll
            for (int j = 0; j < 4; ++j) bb[j] = Bs[k][tx + 16 * j];
#pragma unroll
            for (int i = 0; i < 4; ++i)
#pragma unroll
                for (int j = 0; j < 4; ++j) acc[i][j] += a[i] * bb[j];
        }
    }

#pragma unroll
    for (int i = 0; i < 4; ++i) {
        const int r = m0 + ty + 16 * i;
        if (r >= M) continue;
#pragma unroll
        for (int j = 0; j < 4; ++j) {
            const int c = n0 + tx + 16 * j;
            float vv = alpha * acc[i][j];
            if (bias) vv += bias[c];
            if (Cres) vv += Cres[cOff + (long)r * ldc + c];
            if (relu) vv = fmaxf(vv, 0.f);
            C[cOff + (long)r * ldc + c] = vv;
        }
    }
}

// ---------------------------------------------------------------------------
// qW[b,h,l,c] = sum_d q[b,l,h*64+d] * Wk[h*64+d, c]
// One block per (b,h). K=64.
// ---------------------------------------------------------------------------
__global__ __launch_bounds__(256) void qw_kernel(
    const float* __restrict__ q, const float* __restrict__ Wk,
    float* __restrict__ qw)
{
    const int bz = blockIdx.x;           // 0..127
    const int b = bz >> 3, h = bz & 7;
    __shared__ float q_s[L_][64];        // 25.6 KB

    const int tid = threadIdx.x;
#pragma unroll
    for (int t = 0; t < 25; ++t) {
        const int idx = tid + 256 * t;   // 6400 elems
        const int l = idx >> 6, d = idx & 63;
        q_s[l][d] = q[((long)(b * L_ + l)) * D_ + h * 64 + d];
    }
    __syncthreads();

    const float* Wh = Wk + (long)h * 64 * D_;
    for (int lb = 0; lb < 10; ++lb) {
        float acc0[10], acc1[10];
#pragma unroll
        for (int ll = 0; ll < 10; ++ll) { acc0[ll] = 0.f; acc1[ll] = 0.f; }
        for (int d = 0; d < 64; ++d) {
            const float w0 = Wh[(long)d * D_ + tid];
            const float w1 = Wh[(long)d * D_ + tid + 256];
#pragma unroll
            for (int ll = 0; ll < 10; ++ll) {
                const float qv = q_s[lb * 10 + ll][d];   // broadcast
                acc0[ll] += qv * w0;
                acc1[ll] += qv * w1;
            }
        }
#pragma unroll
        for (int ll = 0; ll < 10; ++ll) {
            const long o = (((long)(b * H_ + h)) * L_ + lb * 10 + ll) * D_;
            qw[o + tid] = acc0[ll];
            qw[o + tid + 256] = acc1[ll];
        }
    }
}

// ---------------------------------------------------------------------------
// Flash kernel: per block (b, 4 l's): for all 8 heads,
//   S[hl,m] = qw[hl,:] . feats[m,:]   (raw scores; head-sum -> mask output)
//   online softmax over m; ctx[hl,:] += p . feats  (unnormalized, /= sum at end)
// 400 blocks, 256 threads, m-chunks of 128, d-chunks of 64.
// LDS ~116 KB -> 1 block/CU.
// ---------------------------------------------------------------------------
#define LT 4
#define HL 32
#define MT 128

__global__ __launch_bounds__(256) void flash_attn(
    const float* __restrict__ qw, const float* __restrict__ feats,
    float* __restrict__ ctx, float* __restrict__ mask_out)
{
    __shared__ float qw_s[HL][516];      // 66 KB (516: float4-aligned rows)
    __shared__ float feats_s[MT][65];    // 33.3 KB (65: odd pad -> conflict-free)
    __shared__ float s_s[HL][MT + 1];    // 16.5 KB
    __shared__ float alpha_s[HL];
    __shared__ float sum_s[HL];

    const int tid = threadIdx.x;
    const int blk = blockIdx.x;
    const int b = blk / 25;
    const int l0 = (blk % 25) * LT;

    // stage qw rows (hl = h*4 + li)
#pragma unroll
    for (int t = 0; t < 16; ++t) {
        const int f4 = tid + 256 * t;    // 4096 float4
        const int hl = f4 >> 7;
        const int c4 = f4 & 127;
        const int h = hl >> 2, li = hl & 3;
        const float4 v = *(const float4*)&qw[(((long)(b * H_ + h)) * L_ + (l0 + li)) * D_ + c4 * 4];
        *(float4*)&qw_s[hl][c4 * 4] = v;
    }

    const int ht = tid >> 5;     // 0..7 : hl tile = {ht, ht+8, ht+16, ht+24}
    const int mt = tid & 31;     // m tile = {mt, mt+32, mt+64, mt+96}
    const int srow = tid >> 3;   // softmax row 0..31
    const int slan = tid & 7;    // 8 lanes per row
    const int cg = tid & 31;     // ctx column lane

    float run_max = -INFINITY, run_sum = 0.f;
    float acc[4][16];            // [hl tile][dc*2+e] -> c = dc*64 + cg + 32*e
#pragma unroll
    for (int i = 0; i < 4; ++i)
#pragma unroll
        for (int k = 0; k < 16; ++k) acc[i][k] = 0.f;

    for (int m0 = 0; m0 < HW_; m0 += MT) {
        float sc[4][4];
#pragma unroll
        for (int i = 0; i < 4; ++i)
#pragma unroll
            for (int j = 0; j < 4; ++j) sc[i][j] = 0.f;

        // ---- pass A: scores, 8 d-chunks ----
        for (int dc = 0; dc < 8; ++dc) {
            __syncthreads();   // previous consumers of feats_s / s_s done
#pragma unroll
            for (int t = 0; t < 8; ++t) {
                const int f4 = tid + 256 * t;   // 2048 float4
                const int r = f4 >> 4;
                const int c4 = f4 & 15;
                const float4 v = *(const float4*)&feats[((long)(b * HW_ + m0 + r)) * D_ + dc * 64 + c4 * 4];
                feats_s[r][c4 * 4 + 0] = v.x;
                feats_s[r][c4 * 4 + 1] = v.y;
                feats_s[r][c4 * 4 + 2] = v.z;
                feats_s[r][c4 * 4 + 3] = v.w;
            }
            __syncthreads();
#pragma unroll 4
            for (int d = 0; d < 64; ++d) {
                float qv[4], fv[4];
#pragma unroll
                for (int i = 0; i < 4; ++i) qv[i] = qw_s[ht + 8 * i][dc * 64 + d];
#pragma unroll
                for (int j = 0; j < 4; ++j) fv[j] = feats_s[mt + 32 * j][d];
#pragma unroll
                for (int i = 0; i < 4; ++i)
#pragma unroll
                    for (int j = 0; j < 4; ++j) sc[i][j] += qv[i] * fv[j];
            }
        }
#pragma unroll
        for (int i = 0; i < 4; ++i)
#pragma unroll
            for (int j = 0; j < 4; ++j) s_s[ht + 8 * i][mt + 32 * j] = sc[i][j];
        __syncthreads();

        // ---- mask: sum of raw scores over heads ----
        {
            const int li = tid >> 6;
            const int mm = tid & 63;
#pragma unroll
            for (int rep = 0; rep < 2; ++rep) {
                const int m = mm + 64 * rep;
                float s = 0.f;
#pragma unroll
                for (int hh = 0; hh < 8; ++hh) s += s_s[hh * 4 + li][m];
                mask_out[((long)(b * L_ + l0 + li)) * HW_ + m0 + m] = s;
            }
        }
        __syncthreads();   // mask reads done before p overwrites s_s

        // ---- online softmax per row ----
        {
            float v[16];
            float mx = -INFINITY;
#pragma unroll
            for (int k = 0; k < 16; ++k) {
                v[k] = s_s[srow][slan * 16 + k];
                mx = fmaxf(mx, v[k]);
            }
#pragma unroll
            for (int o = 4; o > 0; o >>= 1) mx = fmaxf(mx, __shfl_xor(mx, o, 8));
            const float nm = fmaxf(run_max, mx);
            const float al = __expf(run_max - nm);   // first chunk: exp(-inf)=0
            float cs = 0.f;
#pragma unroll
            for (int k = 0; k < 16; ++k) {
                const float p = __expf(v[k] - nm);
                s_s[srow][slan * 16 + k] = p;
                cs += p;
            }
#pragma unroll
            for (int o = 4; o > 0; o >>= 1) cs += __shfl_xor(cs, o, 8);
            run_sum = run_sum * al + cs;
            run_max = nm;
            if (slan == 0) alpha_s[srow] = al;
        }
        __syncthreads();

        // rescale ctx accumulators
#pragma unroll
        for (int i = 0; i < 4; ++i) {
            const float al = alpha_s[ht + 8 * i];
#pragma unroll
            for (int k = 0; k < 16; ++k) acc[i][k] *= al;
        }

        // ---- pass B: ctx += P @ feats, 8 d-chunks (restaged) ----
        for (int dc = 0; dc < 8; ++dc) {
            __syncthreads();
#pragma unroll
            for (int t = 0; t < 8; ++t) {
                const int f4 = tid + 256 * t;
                const int r = f4 >> 4;
                const int c4 = f4 & 15;
                const float4 v = *(const float4*)&feats[((long)(b * HW_ + m0 + r)) * D_ + dc * 64 + c4 * 4];
                feats_s[r][c4 * 4 + 0] = v.x;
                feats_s[r][c4 * 4 + 1] = v.y;
                feats_s[r][c4 * 4 + 2] = v.z;
                feats_s[r][c4 * 4 + 3] = v.w;
            }
            __syncthreads();
#pragma unroll 2
            for (int m = 0; m < MT; ++m) {
                float p[4];
#pragma unroll
                for (int i = 0; i < 4; ++i) p[i] = s_s[ht + 8 * i][m];   // broadcast
                const float f0 = feats_s[m][cg];
                const float f1 = feats_s[m][cg + 32];
#pragma unroll
                for (int i = 0; i < 4; ++i) {
                    acc[i][2 * dc]     += p[i] * f0;
                    acc[i][2 * dc + 1] += p[i] * f1;
                }
            }
        }
    }

    // ---- writeout: normalize by softmax denominator ----
    if (slan == 0) sum_s[srow] = run_sum;
    __syncthreads();
#pragma unroll
    for (int i = 0; i < 4; ++i) {
        const int hl = ht + 8 * i;
        const float inv = 1.f / sum_s[hl];
        const int h = hl >> 2, li = hl & 3;
        const long base = (((long)(b * H_ + h)) * L_ + (l0 + li)) * D_;
#pragma unroll
        for (int dc = 0; dc < 8; ++dc) {
            ctx[base + dc * 64 + cg]      = acc[i][2 * dc] * inv;
            ctx[base + dc * 64 + cg + 32] = acc[i][2 * dc + 1] * inv;
        }
    }
}

// ---------------------------------------------------------------------------
// Row LayerNorm over 512 cols. One block per row.
// ---------------------------------------------------------------------------
__global__ __launch_bounds__(256) void ln_kernel(
    const float* __restrict__ X, const float* __restrict__ w,
    const float* __restrict__ bb, float* __restrict__ out)
{
    const int row = blockIdx.x;
    const int tid = threadIdx.x;
    const long base = (long)row * D_;
    const float x0 = X[base + tid];
    const float x1 = X[base + tid + 256];
    float s = x0 + x1;
    float sq = x0 * x0 + x1 * x1;
#pragma unroll
    for (int o = 32; o > 0; o >>= 1) {
        s  += __shfl_xor(s, o, 64);
        sq += __shfl_xor(sq, o, 64);
    }
    __shared__ float ws_[4], wq_[4];
    const int wid = tid >> 6, lane = tid & 63;
    if (lane == 0) { ws_[wid] = s; wq_[wid] = sq; }
    __syncthreads();
    s  = ws_[0] + ws_[1] + ws_[2] + ws_[3];
    sq = wq_[0] + wq_[1] + wq_[2] + wq_[3];
    const float mu = s * (1.f / 512.f);
    const float var = sq * (1.f / 512.f) - mu * mu;
    const float rs = rsqrtf(var + 1e-5f);
    out[base + tid]       = (x0 - mu) * rs * w[tid] + bb[tid];
    out[base + tid + 256] = (x1 - mu) * rs * w[tid + 256] + bb[tid + 256];
}

// ---------------------------------------------------------------------------
extern "C" void kernel_launch(void* const* d_in, const int* in_sizes, int n_in,
                              void* d_out, int out_size, void* d_ws, size_t ws_size,
                              hipStream_t stream)
{
    const float* query = (const float*)d_in[0];
    const float* feats = (const float*)d_in[1];
    const float* Wq    = (const float*)d_in[2];
    const float* Wk    = (const float*)d_in[3];
    const float* Wv    = (const float*)d_in[4];
    const float* Wp    = (const float*)d_in[5];
    const float* bp    = (const float*)d_in[6];
    const float* W1    = (const float*)d_in[7];
    const float* b1    = (const float*)d_in[8];
    const float* W2    = (const float*)d_in[9];
    const float* b2    = (const float*)d_in[10];
    const float* ln0w  = (const float*)d_in[11];
    const float* ln0b  = (const float*)d_in[12];
    const float* ln2w  = (const float*)d_in[13];
    const float* ln2b  = (const float*)d_in[14];

    float* out = (float*)d_out;            // [y: 819200][mask: 26214400]
    float* ws  = (float*)d_ws;

    // ws layout (floats). Total used: 13,926,400 floats = 53.2 MiB.
    float* q     = ws;                     //   819,200
    float* qw    = ws + 819200;            // 6,553,600
    float* ctx   = ws + 7372800;           // 6,553,600
    float* attno = ws;                     // reuse q region (dead after qw_kernel)
    float* xin   = ws + 7372800;           // reuse ctx region (dead after Wv proj)
    float* x     = xin + 819200;
    float* h1    = x + 819200;
    float* ffnp  = h1 + 819200;

    const dim3 thr(256);

    // q = 0.125 * query @ Wq.T        [1600 x 512, K=512]
    gemm_bt<<<dim3(8, 25, 1), thr, 0, stream>>>(
        query, Wq, nullptr, nullptr, q,
        1600, 512, 512, 512, 512, 512, 1, 0, 0, 0, 0, 0.125f, 0);

    // qW[b,h,l,:] = q_head @ Wk_head
    qw_kernel<<<dim3(128), thr, 0, stream>>>(q, Wk, qw);

    // fused scores + mask + online softmax + ctx accumulation
    flash_attn<<<dim3(400), thr, 0, stream>>>(qw, feats, ctx, out + 819200);

    // attno[b,l,h*64+d] = ctx[b,h,l,:] . Wv[h*64+d,:]  (batched over 128 (b,h))
    gemm_bt<<<dim3(1, 2, 128), thr, 0, stream>>>(
        ctx, Wv, nullptr, nullptr, attno,
        100, 64, 512, 512, 512, 512, 8, 51200, 32768, 51200, 64, 1.f, 0);

    // xin = query + attno @ Wp.T + bp
    gemm_bt<<<dim3(8, 25, 1), thr, 0, stream>>>(
        attno, Wp, query, bp, xin,
        1600, 512, 512, 512, 512, 512, 1, 0, 0, 0, 0, 1.f, 0);

    // x = LN0(xin)
    ln_kernel<<<dim3(1600), thr, 0, stream>>>(xin, ln0w, ln0b, x);

    // h1 = relu(x @ W1.T + b1)
    gemm_bt<<<dim3(8, 25, 1), thr, 0, stream>>>(
        x, W1, nullptr, b1, h1,
        1600, 512, 512, 512, 512, 512, 1, 0, 0, 0, 0, 1.f, 1);

    // ffnp = x + h1 @ W2.T + b2
    gemm_bt<<<dim3(8, 25, 1), thr, 0, stream>>>(
        h1, W2, x, b2, ffnp,
        1600, 512, 512, 512, 512, 512, 1, 0, 0, 0, 0, 1.f, 0);

    // y = LN2(ffnp) -> d_out
    ln_kernel<<<dim3(1600), thr, 0, stream>>>(ffnp, ln2w, ln2b, out);
}